// Round 3
// baseline (303.823 us; speedup 1.0000x reference)
//
#include <hip/hip_runtime.h>

// ---------------------------------------------------------------------------
// unit_gcn: out[n,o,t,v] = BN+ReLU of  sum_{s=0..24} Ws[s] @_c x[n,:,t,(v+s)%25]
//   Ws[0] = sum_i W[i,:,:,0];  Ws[s] = W[s-1,:,:,1]  (s>=1); bias cancels in BN.
// N=64, C=64, T=300, V=25, O=64.  x fp32 -> bf16 MFMA (16x16x32), fp32 accum.
// ---------------------------------------------------------------------------

typedef short  s16x8 __attribute__((ext_vector_type(8)));
typedef float  f32x4 __attribute__((ext_vector_type(4)));

#define T_      300
#define TB_     19          // ceil(300/16) t-blocks
#define NTHR_   320         // 5 waves per block
#define ASTRIDE 136         // padded A-slab row stride in bytes (2-way banks, linear addr)
#define TSTR    404         // padded epilogue transpose stride (f32 units)

__device__ __forceinline__ unsigned short f2bf(float f) {
  unsigned u = __builtin_bit_cast(unsigned, f);
  return (unsigned short)((u + 0x7FFFu + ((u >> 16) & 1u)) >> 16);
}

// --- P0: pack Ws into MFMA B-fragment layout -------------------------------
// Wg entry idx = ((s*2+chunk)*4 + ni)*64 + lane ; 8 bf16 per entry:
//   elem j = Ws[s][ o = ni*16 + (lane&15) ][ c = chunk*32 + (lane>>4)*8 + j ]
__global__ void pack_w_kernel(const float* __restrict__ W, s16x8* __restrict__ Wg) {
  int idx = blockIdx.x * 256 + threadIdx.x;
  if (idx >= 12800) return;
  int lane  = idx & 63;
  int ni    = (idx >> 6) & 3;
  int chunk = (idx >> 8) & 1;
  int s     = idx >> 9;
  int o     = (ni << 4) + (lane & 15);
  int cbase = (chunk << 5) + ((lane >> 4) << 3);
  s16x8 h;
#pragma unroll
  for (int j = 0; j < 8; ++j) {
    int c = cbase + j;
    float val;
    if (s == 0) {
      val = 0.f;
      for (int i = 0; i < 24; ++i) val += W[((i * 64 + o) * 64 + c) * 2];
    } else {
      val = W[(((s - 1) * 64 + o) * 64 + c) * 2 + 1];
    }
    h[j] = (short)f2bf(val);
  }
  Wg[idx] = h;
}

// --- P1: main tap-GEMM -----------------------------------------------------
// grid (n=64, tb=19), 320 threads = 5 waves. Block owns rows (t_local,v)=400,
// cols o=64. A-slab [400 rows][64 c] bf16 in LDS, padded stride 136 B.
// Wave w: 5 row-tiles x 4 col-tiles, acc 5x4 f32x4. q-loop = s*2+chunk,
// A-frags prefetched 1 phase ahead (rotate regs), B-frags 2 phases ahead.
__global__ __launch_bounds__(NTHR_) void tap_mm_kernel(
    const float* __restrict__ x, const s16x8* __restrict__ Wg,
    float* __restrict__ out, float* __restrict__ partials) {
  __shared__ __align__(16) char Ash[54400];   // A-slab; later T[32][TSTR] f32 (51712 B)
  __shared__ float red2[640];
  int n  = blockIdx.x;
  int tb = blockIdx.y;
  int t0 = tb * 16;
  int validRows = min(16, T_ - t0) * 25;
  int tid = threadIdx.x;
  const float* xn = x + n * 480000 + t0 * 25;

  // ---- stage A: 8 strided c-values -> one 16B ds_write (2-way banks, free)
#pragma unroll 5
  for (int it = 0; it < 10; ++it) {
    int id  = tid + it * NTHR_;        // cgroup*400 + pos
    int pos = id % 400;                // t_local*25 + u (contiguous in x)
    int c0  = (id / 400) << 3;
    bool vld = pos < validRows;
    s16x8 h;
#pragma unroll
    for (int j = 0; j < 8; ++j) {
      float f = vld ? xn[(c0 + j) * 7500 + pos] : 0.f;
      h[j] = (short)f2bf(f);
    }
    *(s16x8*)(Ash + pos * ASTRIDE + (c0 << 1)) = h;
  }

  int wid = tid >> 6, lane = tid & 63;
  int l15 = lane & 15, lk = lane >> 4;
  int u[5], ao[5];                      // ao = srow*ASTRIDE + lk*16 (chunk0 addr)
#pragma unroll
  for (int r = 0; r < 5; ++r) {
    int orow = ((wid * 5 + r) << 4) + l15;   // A-side row this lane feeds
    int tL = orow / 25;
    u[r]  = orow - tL * 25;                  // = v; advances with s
    ao[r] = orow * ASTRIDE + (lk << 4);
  }
  f32x4 acc[5][4];
#pragma unroll
  for (int r = 0; r < 5; ++r)
#pragma unroll
    for (int ct = 0; ct < 4; ++ct) acc[r][ct] = (f32x4){0.f, 0.f, 0.f, 0.f};

  // B-frag ring: 2 phases deep (q, q+1 in regs; q+2 issued during phase q)
  s16x8 bf[2][4];
#pragma unroll
  for (int ni = 0; ni < 4; ++ni) bf[0][ni] = Wg[(ni << 6) + lane];         // q=0
#pragma unroll
  for (int ni = 0; ni < 4; ++ni) bf[1][ni] = Wg[256 + (ni << 6) + lane];   // q=1

  __syncthreads();

  // A-frag preload for q=0 (chunk0 of s=0)
  s16x8 af[5];
#pragma unroll
  for (int r = 0; r < 5; ++r) af[r] = *(const s16x8*)(Ash + ao[r]);

#pragma unroll 2
  for (int q = 0; q < 50; ++q) {
    int cur = q & 1;
    // prefetch A-frags for q+1
    s16x8 nxt[5];
    if (cur == 0) {                    // next = chunk1, same s: +64 B
#pragma unroll
      for (int r = 0; r < 5; ++r) nxt[r] = *(const s16x8*)(Ash + ao[r] + 64);
    } else {                           // next = chunk0 of s+1: advance shift
#pragma unroll
      for (int r = 0; r < 5; ++r) {
        bool w = (u[r] == 24);
        u[r]  = w ? 0 : u[r] + 1;
        ao[r] += w ? -(24 * ASTRIDE) : ASTRIDE;
        nxt[r] = *(const s16x8*)(Ash + ao[r]);
      }
    }
    __builtin_amdgcn_s_setprio(1);
#pragma unroll
    for (int r = 0; r < 5; ++r)
#pragma unroll
      for (int ct = 0; ct < 4; ++ct)
        acc[r][ct] = __builtin_amdgcn_mfma_f32_16x16x32_bf16(
            af[r], bf[cur][ct], acc[r][ct], 0, 0, 0);
    __builtin_amdgcn_s_setprio(0);
    // issue B loads for q+2 into the slot just consumed (uniform index -> SALU)
    int nq = q + 2; nq = (nq >= 50) ? nq - 50 : nq;   // wrap -> harmless dummy
#pragma unroll
    for (int ni = 0; ni < 4; ++ni) bf[cur][ni] = Wg[(nq << 8) + (ni << 6) + lane];
#pragma unroll
    for (int r = 0; r < 5; ++r) af[r] = nxt[r];
  }

  // ---- per-channel sum/sumsq from registers (valid rows only)
  float s1v[4] = {0.f, 0.f, 0.f, 0.f}, s2v[4] = {0.f, 0.f, 0.f, 0.f};
#pragma unroll
  for (int r = 0; r < 5; ++r) {
#pragma unroll
    for (int qq = 0; qq < 4; ++qq) {
      int orow = ((wid * 5 + r) << 4) + (lk << 2) + qq;  // C/D: row=(l>>4)*4+reg
      if (orow < validRows) {
#pragma unroll
        for (int ct = 0; ct < 4; ++ct) {
          float val = acc[r][ct][qq];
          s1v[ct] += val;
          s2v[ct] += val * val;
        }
      }
    }
  }
#pragma unroll
  for (int ct = 0; ct < 4; ++ct) {
    float a = s1v[ct], b = s2v[ct];
    a += __shfl_xor(a, 16); a += __shfl_xor(a, 32);
    b += __shfl_xor(b, 16); b += __shfl_xor(b, 32);
    if (lane < 16) {
      int base = ((((wid << 2) + ct) << 4) + l15) * 2;
      red2[base]     = a;
      red2[base + 1] = b;
    }
  }

  // ---- epilogue: two o-halves through LDS transpose, coalesced f4 stores
  float* T = (float*)Ash;
  float* outb = out + n * 480000 + tb * 400;   // + o*7500 + row
#pragma unroll
  for (int h = 0; h < 2; ++h) {
    __syncthreads();   // h=0: all Ash reads + red2 writes done; h=1: T reads done
    // write acc -> T[o_local][row]  (stride 404 f32 -> ~2-way banks)
#pragma unroll
    for (int r = 0; r < 5; ++r)
#pragma unroll
      for (int ctl = 0; ctl < 2; ++ctl) {
        int o_local = (ctl << 4) + l15;
        int row0    = wid * 80 + r * 16 + (lk << 2);
        *(f32x4*)&T[o_local * TSTR + row0] = acc[r][(h << 1) + ctl];
      }
    __syncthreads();
    if (h == 0 && tid < 128) {   // deterministic partial reduction (reads red2)
      int o = tid >> 1, m = tid & 1;
      int ct = o >> 4, ol = o & 15;
      float sres = 0.f;
#pragma unroll
      for (int w = 0; w < 5; ++w) sres += red2[((((w << 2) + ct) << 4) + ol) * 2 + m];
      int bl = blockIdx.y * 64 + blockIdx.x;
      partials[bl * 128 + m * 64 + o] = sres;
    }
    // read T + coalesced global f4 stores: 32 o x 100 f4-rows
#pragma unroll
    for (int i = 0; i < 10; ++i) {
      int idx = tid + i * 320;
      int ol  = idx / 100;
      int r4  = idx - ol * 100;
      if ((r4 << 2) < validRows) {
        float4 v = *(float4*)&T[ol * TSTR + (r4 << 2)];
        *(float4*)&outb[((h << 5) + ol) * 7500 + (r4 << 2)] = v;
      }
    }
  }
}

// --- P2: reduce per-block partials -> per-channel scale/shift --------------
__global__ void finalize_kernel(const float* __restrict__ part,
                                const float* __restrict__ gamma,
                                const float* __restrict__ beta,
                                float* __restrict__ scsh) {
  __shared__ float sm[512];
  int o = blockIdx.x;            // 64 blocks, one channel each
  int tid = threadIdx.x;         // 256 threads
  float s1 = 0.f, s2 = 0.f;
  for (int b = tid; b < 1216; b += 256) {
    s1 += part[b * 128 + o];
    s2 += part[b * 128 + 64 + o];
  }
  sm[tid] = s1; sm[256 + tid] = s2;
  __syncthreads();
  for (int st = 128; st >= 1; st >>= 1) {
    if (tid < st) { sm[tid] += sm[tid + st]; sm[256 + tid] += sm[256 + tid + st]; }
    __syncthreads();
  }
  if (tid == 0) {
    const float inv = 1.0f / 480000.0f;
    float mean = sm[0] * inv;
    float var  = sm[256] * inv - mean * mean;
    float sc = gamma[o] * rsqrtf(var + 1e-5f);
    float sh = beta[o] - mean * sc;
    scsh[o]      = sc;
    scsh[64 + o] = sh;
  }
}

// --- P3: in-place BN-apply + ReLU, float4 ----------------------------------
__global__ void bn_relu_kernel(float4* __restrict__ out, const float* __restrict__ scsh) {
  int i = blockIdx.x * blockDim.x + threadIdx.x;
  const int total = 7680000;        // 30.72M / 4 ; 7500%4==0 so o uniform per f4
  int stride = gridDim.x * blockDim.x;
  for (; i < total; i += stride) {
    int o = (i / 1875) & 63;
    float sc = scsh[o], sh = scsh[64 + o];
    float4 v = out[i];
    v.x = fmaxf(fmaf(v.x, sc, sh), 0.f);
    v.y = fmaxf(fmaf(v.y, sc, sh), 0.f);
    v.z = fmaxf(fmaf(v.z, sc, sh), 0.f);
    v.w = fmaxf(fmaf(v.w, sc, sh), 0.f);
    out[i] = v;
  }
}

// ---------------------------------------------------------------------------
extern "C" void kernel_launch(void* const* d_in, const int* in_sizes, int n_in,
                              void* d_out, int out_size, void* d_ws, size_t ws_size,
                              hipStream_t stream) {
  const float* x     = (const float*)d_in[0];
  const float* W     = (const float*)d_in[1];
  // d_in[2] = b : cancels under batch-norm, unused.
  const float* gamma = (const float*)d_in[3];
  const float* beta  = (const float*)d_in[4];
  float* out = (float*)d_out;

  char* ws = (char*)d_ws;
  s16x8* Wg       = (s16x8*)ws;                       // 204,800 B
  float* partials = (float*)(ws + 204800);            // 1216*128*4 = 622,592 B
  float* scsh     = (float*)(ws + 204800 + 622592);   // 512 B

  pack_w_kernel<<<dim3(50), dim3(256), 0, stream>>>(W, Wg);
  tap_mm_kernel<<<dim3(64, TB_), dim3(NTHR_), 0, stream>>>(x, Wg, out, partials);
  finalize_kernel<<<dim3(64), dim3(256), 0, stream>>>(partials, gamma, beta, scsh);
  bn_relu_kernel<<<dim3(2048), dim3(256), 0, stream>>>((float4*)out, scsh);
}